// Round 2
// baseline (556.749 us; speedup 1.0000x reference)
//
#include <hip/hip_runtime.h>
#include <math.h>

#define EPSF 1e-5f

// ---------------- K1: node transforms  P = x @ {Wf_i, Ws_i, Wf_j, Ws_j} (+bias) ----
__global__ __launch_bounds__(256) void node_gemm(
    const float* __restrict__ x, const float* __restrict__ Wf,
    const float* __restrict__ bf, const float* __restrict__ Ws,
    const float* __restrict__ bs, float* __restrict__ Pdst,
    float* __restrict__ Psrc, int N) {
  const int lane = threadIdx.x & 63;
  const int w = threadIdx.x >> 6;
  const float* W = (w & 1) ? Ws : Wf;
  const int baseRow = (w >> 1) * 64;
  float wreg[64];
#pragma unroll
  for (int k = 0; k < 64; ++k) wreg[k] = W[(baseRow + k) * 64 + lane];
  float bias = 0.f;
  if (w == 0) bias = bf[lane];
  if (w == 1) bias = bs[lane];
  float* outp = (w >> 1) ? Psrc : Pdst;
  const int outOff = (w & 1) * 64;

  for (int n = blockIdx.x; n < N; n += gridDim.x) {
    const float* xr = x + (size_t)n * 64;
    float acc = bias;
#pragma unroll
    for (int k = 0; k < 64; k += 4) {
      float4 xv = *(const float4*)(xr + k);
      acc = fmaf(xv.x, wreg[k], acc);
      acc = fmaf(xv.y, wreg[k + 1], acc);
      acc = fmaf(xv.z, wreg[k + 2], acc);
      acc = fmaf(xv.w, wreg[k + 3], acc);
    }
    outp[(size_t)n * 128 + outOff + lane] = acc;
  }
}

// ---------------- CSR build: histogram of dst ----------------
__global__ void hist_kernel(const int* __restrict__ ei, int* __restrict__ deg,
                            int E) {
  int i = blockIdx.x * blockDim.x + threadIdx.x;
  if (i < E) atomicAdd(&deg[ei[E + i]], 1);
}

// ---------------- CSR build: exclusive scan (single block, 4/thread) --------
__global__ __launch_bounds__(1024) void scan_kernel(
    const int* __restrict__ deg, int* __restrict__ offsets,
    int* __restrict__ cursor, int N) {
  __shared__ int wsum[16];
  __shared__ int carry_s;
  const int t = threadIdx.x;
  const int lane = t & 63;
  const int w = t >> 6;
  if (t == 0) carry_s = 0;
  __syncthreads();
  for (int base = 0; base < N; base += 4096) {
    int i0 = base + t * 4;
    int d0 = (i0 < N) ? deg[i0] : 0;
    int d1 = (i0 + 1 < N) ? deg[i0 + 1] : 0;
    int d2 = (i0 + 2 < N) ? deg[i0 + 2] : 0;
    int d3 = (i0 + 3 < N) ? deg[i0 + 3] : 0;
    int s = d0 + d1 + d2 + d3;
    int sc = s;
#pragma unroll
    for (int o = 1; o < 64; o <<= 1) {
      int v = __shfl_up(sc, o);
      if (lane >= o) sc += v;
    }
    if (lane == 63) wsum[w] = sc;
    __syncthreads();
    int c = carry_s;
    int woff = 0, total = 0;
#pragma unroll
    for (int k = 0; k < 16; ++k) {
      woff += (k < w) ? wsum[k] : 0;
      total += wsum[k];
    }
    int e0 = c + woff + (sc - s);
    int e1 = e0 + d0, e2 = e1 + d1, e3 = e2 + d2;
    if (i0 < N) { offsets[i0] = e0; cursor[i0] = e0; }
    if (i0 + 1 < N) { offsets[i0 + 1] = e1; cursor[i0 + 1] = e1; }
    if (i0 + 2 < N) { offsets[i0 + 2] = e2; cursor[i0 + 2] = e2; }
    if (i0 + 3 < N) { offsets[i0 + 3] = e3; cursor[i0 + 3] = e3; }
    __syncthreads();
    if (t == 0) carry_s = c + total;
    __syncthreads();
  }
  if (t == 0) offsets[N] = carry_s;
}

// ---------------- CSR build: scatter (eattr_idx, src) pairs -----------------
__global__ void scatter_kernel(const int* __restrict__ ei,
                               int* __restrict__ cursor,
                               int2* __restrict__ epair, int E) {
  int i = blockIdx.x * blockDim.x + threadIdx.x;
  if (i < E) {
    int dst = ei[E + i];
    int pos = atomicAdd(&cursor[dst], 1);
    epair[pos] = make_int2(i, ei[i]);
  }
}

// ---------------- K2: per-node edge aggregation (atomic-free) ----------------
// One wave per dst node; lane = feature. Edge weights (rows 128..159) in VGPRs.
__global__ __launch_bounds__(256) void edge_agg(
    const int* __restrict__ offsets, const int2* __restrict__ epair,
    const float* __restrict__ eattr, const float* __restrict__ Wf,
    const float* __restrict__ Ws, const float* __restrict__ Pdst,
    const float* __restrict__ Psrc, float* __restrict__ agg, int N,
    int nWaves) {
  const int lane = threadIdx.x & 63;
  const int wid = blockIdx.x * (blockDim.x >> 6) + (threadIdx.x >> 6);
  float wf[32], wsr[32];
#pragma unroll
  for (int k = 0; k < 32; ++k) {
    wf[k] = Wf[(128 + k) * 64 + lane];
    wsr[k] = Ws[(128 + k) * 64 + lane];
  }
  for (int n = wid; n < N; n += nWaves) {
    const int o0 = offsets[n];
    const int o1 = offsets[n + 1];
    const float fb = Pdst[(size_t)n * 128 + lane];
    const float sb = Pdst[(size_t)n * 128 + 64 + lane];
    float acc = 0.f;
    for (int j = o0; j < o1; ++j) {
      int2 p = epair[j];
      const float* er = eattr + (size_t)p.x * 32;
      const float* pr = Psrc + (size_t)p.y * 128;
      float f = fb + pr[lane];
      float s = sb + pr[64 + lane];
#pragma unroll
      for (int k = 0; k < 32; k += 4) {
        float4 ev = *(const float4*)(er + k);
        f = fmaf(ev.x, wf[k], f);     s = fmaf(ev.x, wsr[k], s);
        f = fmaf(ev.y, wf[k + 1], f); s = fmaf(ev.y, wsr[k + 1], s);
        f = fmaf(ev.z, wf[k + 2], f); s = fmaf(ev.z, wsr[k + 2], s);
        f = fmaf(ev.w, wf[k + 3], f); s = fmaf(ev.w, wsr[k + 3], s);
      }
      float sig = __builtin_amdgcn_rcpf(1.0f + __expf(-f));
      float sp = fmaxf(s, 0.f) + __logf(1.0f + __expf(-fabsf(s)));
      acc += sig * sp;
    }
    agg[(size_t)n * 64 + lane] = acc;
  }
}

// ---------------- K3: per-feature reductions over agg and x ----------------
__global__ __launch_bounds__(256) void stats_kernel(
    const float* __restrict__ agg, const float* __restrict__ x,
    float* __restrict__ stats, int N) {
  const int f = threadIdx.x & 63;
  const int sub = threadIdx.x >> 6;
  float sa = 0, sa2 = 0, sx = 0, sx2 = 0, sax = 0;
  for (int r = blockIdx.x * 4 + sub; r < N; r += gridDim.x * 4) {
    float a = agg[(size_t)r * 64 + f];
    float xv = x[(size_t)r * 64 + f];
    sa += a; sa2 += a * a; sx += xv; sx2 += xv * xv; sax += a * xv;
  }
  __shared__ float lds[4][5][64];
  lds[sub][0][f] = sa; lds[sub][1][f] = sa2; lds[sub][2][f] = sx;
  lds[sub][3][f] = sx2; lds[sub][4][f] = sax;
  __syncthreads();
  if (sub == 0) {
#pragma unroll
    for (int i = 0; i < 5; ++i) {
      float v = lds[0][i][f] + lds[1][i][f] + lds[2][i][f] + lds[3][i][f];
      atomicAdd(&stats[i * 64 + f], v);
    }
  }
}

// ---------------- K4: finalize BN affine + analytic LN stats ----------------
__global__ __launch_bounds__(64) void finalize_stats(
    const float* __restrict__ stats, const float* __restrict__ bn_w,
    const float* __restrict__ bn_b, float* __restrict__ ab, int N) {
  const int f = threadIdx.x;
  const float Nf = (float)N;
  const float invN = 1.0f / Nf;
  float Sa = stats[f], Sa2 = stats[64 + f], Sx = stats[128 + f],
        Sx2 = stats[192 + f], Sax = stats[256 + f];
  float mu = Sa * invN;
  float var = Sa2 * invN - mu * mu;
  float alpha = bn_w[f] / sqrtf(var + EPSF);
  float beta = bn_b[f] - mu * alpha;
  float Sh = alpha * Sa + Nf * beta + Sx;
  float Sh2 = alpha * alpha * Sa2 + Sx2 + Nf * beta * beta +
              2.f * alpha * Sax + 2.f * alpha * beta * Sa + 2.f * beta * Sx;
#pragma unroll
  for (int o = 32; o > 0; o >>= 1) {
    Sh += __shfl_down(Sh, o);
    Sh2 += __shfl_down(Sh2, o);
  }
  ab[f] = alpha;
  ab[64 + f] = beta;
  if (f == 0) {
    float cnt = Nf * 64.0f;
    float mean = Sh / cnt;
    float msq = Sh2 / cnt - mean * mean;
    ab[128] = mean;
    ab[129] = 1.0f / (sqrtf(fmaxf(msq, 0.f)) + EPSF);
  }
}

// ---------------- K5: BN+residual+LN+softplus, pooled into graphs ------------
__global__ __launch_bounds__(256) void node_finish(
    const float* __restrict__ agg, const float* __restrict__ x,
    const int* __restrict__ batch, const float* __restrict__ ab,
    const float* __restrict__ ln_w, const float* __restrict__ ln_b,
    float* __restrict__ add_pool, float* __restrict__ counts, int N,
    int chunk) {
  const int f = threadIdx.x & 63;
  const int sub = threadIdx.x >> 6;
  const int r0 = blockIdx.x * chunk;
  const int r1 = min(N, r0 + chunk);
  const float alpha = ab[f], beta = ab[64 + f];
  const float mean = ab[128], rden = ab[129];
  const float lw = ln_w[f] * rden;
  const float lb = ln_b[f];
  float acc = 0.f, cacc = 0.f;
  int curg = -1;
  for (int r = r0 + sub; r < r1; r += 4) {
    int g = batch[r];
    if (g != curg) {
      if (curg >= 0) {
        atomicAdd(&add_pool[(size_t)curg * 64 + f], acc);
        if (f == 0) atomicAdd(&counts[curg], cacc);
      }
      curg = g; acc = 0.f; cacc = 0.f;
    }
    float h = fmaf(alpha, agg[(size_t)r * 64 + f], beta) + x[(size_t)r * 64 + f];
    float v = (h - mean) * lw + lb;
    float sp = fmaxf(v, 0.f) + __logf(1.0f + __expf(-fabsf(v)));
    acc += sp; cacc += 1.f;
  }
  if (curg >= 0) {
    atomicAdd(&add_pool[(size_t)curg * 64 + f], acc);
    if (f == 0) atomicAdd(&counts[curg], cacc);
  }
}

// ---------------- K6: graph head ----------------
__global__ __launch_bounds__(1024) void graph_out(
    const float* __restrict__ add_pool, const float* __restrict__ counts,
    const float* __restrict__ Wl, const float* __restrict__ bl,
    const float* __restrict__ w4, const float* __restrict__ b4,
    float* __restrict__ out, int G) {
  const int t = threadIdx.x;
  const int g = t >> 1, c = t & 1;
  float cnt = fmaxf(counts[g], 1.0f);
  float inv = 1.0f / cnt;
  const float* ap = add_pool + (size_t)g * 64;
  float v = bl[c];
#pragma unroll 8
  for (int k = 0; k < 64; ++k)
    v = fmaf(ap[k], fmaf(Wl[k * 2 + c], inv, Wl[(64 + k) * 2 + c]), v);

  __shared__ float red[16];
  __shared__ float bc[2];
  float sum = v;
#pragma unroll
  for (int o = 32; o > 0; o >>= 1) sum += __shfl_down(sum, o);
  if ((t & 63) == 0) red[t >> 6] = sum;
  __syncthreads();
  if (t == 0) {
    float tot = 0;
#pragma unroll
    for (int i = 0; i < 16; ++i) tot += red[i];
    bc[0] = tot * (1.0f / 1024.0f);
  }
  __syncthreads();
  const float mean = bc[0];
  const float xc = v - mean;
  float sq = xc * xc;
  __syncthreads();
#pragma unroll
  for (int o = 32; o > 0; o >>= 1) sq += __shfl_down(sq, o);
  if ((t & 63) == 0) red[t >> 6] = sq;
  __syncthreads();
  if (t == 0) {
    float tot = 0;
#pragma unroll
    for (int i = 0; i < 16; ++i) tot += red[i];
    bc[1] = 1.0f / (sqrtf(tot * (1.0f / 1024.0f)) + EPSF);
  }
  __syncthreads();
  out[t] = xc * bc[1] * w4[c] + b4[c];
}

extern "C" void kernel_launch(void* const* d_in, const int* in_sizes, int n_in,
                              void* d_out, int out_size, void* d_ws,
                              size_t ws_size, hipStream_t stream) {
  const float* x = (const float*)d_in[0];
  const int* ei = (const int*)d_in[1];
  const float* eattr = (const float*)d_in[2];
  const int* batch = (const int*)d_in[3];
  const float* Wf = (const float*)d_in[4];
  const float* bf = (const float*)d_in[5];
  const float* Ws = (const float*)d_in[6];
  const float* bs = (const float*)d_in[7];
  const float* bn_w = (const float*)d_in[8];
  const float* bn_b = (const float*)d_in[9];
  const float* ln_w = (const float*)d_in[10];
  const float* ln_b = (const float*)d_in[11];
  const float* Wl = (const float*)d_in[12];
  const float* bl = (const float*)d_in[13];
  const float* w4 = (const float*)d_in[14];
  const float* b4 = (const float*)d_in[15];

  const int N = in_sizes[0] / 64;
  const int E = in_sizes[2] / 32;
  const int G = 512;

  // Workspace layout (elements; all blocks multiple-of-4 elements => 16B align)
  float* ws = (float*)d_ws;
  float* agg = ws;                                   // N*64
  int* offsets = (int*)(agg + (size_t)N * 64);       // N+4
  float* stats = (float*)(offsets + N + 4);          // 320   [zeroed]
  float* add_pool = stats + 320;                     // G*64  [zeroed]
  float* counts = add_pool + (size_t)G * 64;         // G     [zeroed]
  int* deg = (int*)(counts + G);                     // N     [zeroed]
  int* cursor = deg + N;                             // N
  float* ab = (float*)(cursor + N);                  // 132
  int2* epair = (int2*)(ab + 132);                   // E int2 (2E ints)
  float* Pdst = (float*)((int*)epair + 2 * (size_t)E);  // N*128
  float* Psrc = Pdst + (size_t)N * 128;              // N*128

  size_t zeroFloats = 320 + (size_t)G * 64 + G + N;
  hipMemsetAsync(stats, 0, zeroFloats * sizeof(float), stream);

  node_gemm<<<2048, 256, 0, stream>>>(x, Wf, bf, Ws, bs, Pdst, Psrc, N);
  hist_kernel<<<(E + 255) / 256, 256, 0, stream>>>(ei, deg, E);
  scan_kernel<<<1, 1024, 0, stream>>>(deg, offsets, cursor, N);
  scatter_kernel<<<(E + 255) / 256, 256, 0, stream>>>(ei, cursor, epair, E);
  edge_agg<<<2048, 256, 0, stream>>>(offsets, epair, eattr, Wf, Ws, Pdst, Psrc,
                                     agg, N, 2048 * 4);
  stats_kernel<<<512, 256, 0, stream>>>(agg, x, stats, N);
  finalize_stats<<<1, 64, 0, stream>>>(stats, bn_w, bn_b, ab, N);
  const int chunk = (N + 511) / 512;
  node_finish<<<512, 256, 0, stream>>>(agg, x, batch, ab, ln_w, ln_b, add_pool,
                                       counts, N, chunk);
  graph_out<<<1, 1024, 0, stream>>>(add_pool, counts, Wl, bl, w4, b4,
                                    (float*)d_out, G);
}

// Round 3
// 431.445 us; speedup vs baseline: 1.2904x; 1.2904x over previous
//
#include <hip/hip_runtime.h>
#include <math.h>

#define EPSF 1e-5f

// ---------------- K1: node transforms  P = x @ {Wf_i, Ws_i, Wf_j, Ws_j} (+bias) ----
__global__ __launch_bounds__(256, 4) void node_gemm(
    const float* __restrict__ x, const float* __restrict__ Wf,
    const float* __restrict__ bf, const float* __restrict__ Ws,
    const float* __restrict__ bs, float* __restrict__ Pdst,
    float* __restrict__ Psrc, int N) {
  const int lane = threadIdx.x & 63;
  const int w = threadIdx.x >> 6;
  const float* W = (w & 1) ? Ws : Wf;
  const int baseRow = (w >> 1) * 64;
  float wreg[64];
#pragma unroll
  for (int k = 0; k < 64; ++k) wreg[k] = W[(baseRow + k) * 64 + lane];
  float bias = 0.f;
  if (w == 0) bias = bf[lane];
  if (w == 1) bias = bs[lane];
  float* outp = (w >> 1) ? Psrc : Pdst;
  const int outOff = (w & 1) * 64;

  for (int n = blockIdx.x; n < N; n += gridDim.x) {
    const float* xr = x + (size_t)n * 64;
    float acc = bias;
#pragma unroll
    for (int k = 0; k < 64; k += 4) {
      float4 xv = *(const float4*)(xr + k);
      acc = fmaf(xv.x, wreg[k], acc);
      acc = fmaf(xv.y, wreg[k + 1], acc);
      acc = fmaf(xv.z, wreg[k + 2], acc);
      acc = fmaf(xv.w, wreg[k + 3], acc);
    }
    outp[(size_t)n * 128 + outOff + lane] = acc;
  }
}

// ---------------- CSR build: histogram of dst ----------------
__global__ void hist_kernel(const int* __restrict__ ei, int* __restrict__ deg,
                            int E) {
  int i = blockIdx.x * blockDim.x + threadIdx.x;
  if (i < E) atomicAdd(&deg[ei[E + i]], 1);
}

// ---------------- CSR build: exclusive scan (single block, 16/thread) --------
__global__ __launch_bounds__(1024) void scan_kernel(
    const int* __restrict__ deg, int* __restrict__ offsets,
    int* __restrict__ cursor, int N) {
  __shared__ int wsum[16];
  __shared__ int carry_s;
  const int t = threadIdx.x;
  const int lane = t & 63;
  const int w = t >> 6;
  if (t == 0) carry_s = 0;
  __syncthreads();
  const int PER = 16;
  const int PASS = 1024 * PER;  // 16384
  for (int base = 0; base < N; base += PASS) {
    const int i0 = base + t * PER;
    int d[PER];
    int s = 0;
#pragma unroll
    for (int k = 0; k < PER; ++k) {
      int idx = i0 + k;
      d[k] = (idx < N) ? deg[idx] : 0;
      s += d[k];
    }
    int sc = s;
#pragma unroll
    for (int o = 1; o < 64; o <<= 1) {
      int v = __shfl_up(sc, o);
      if (lane >= o) sc += v;
    }
    if (lane == 63) wsum[w] = sc;
    __syncthreads();
    int c = carry_s;
    int woff = 0, total = 0;
#pragma unroll
    for (int k = 0; k < 16; ++k) {
      woff += (k < w) ? wsum[k] : 0;
      total += wsum[k];
    }
    int run = c + woff + (sc - s);
#pragma unroll
    for (int k = 0; k < PER; ++k) {
      int idx = i0 + k;
      if (idx < N) { offsets[idx] = run; cursor[idx] = run; }
      run += d[k];
    }
    __syncthreads();
    if (t == 0) carry_s = c + total;
    __syncthreads();
  }
  if (t == 0) offsets[N] = carry_s;
}

// ---------------- CSR build: scatter (eattr_idx, src) pairs -----------------
__global__ void scatter_kernel(const int* __restrict__ ei,
                               int* __restrict__ cursor,
                               int2* __restrict__ epair, int E) {
  int i = blockIdx.x * blockDim.x + threadIdx.x;
  if (i < E) {
    int dst = ei[E + i];
    int pos = atomicAdd(&cursor[dst], 1);
    epair[pos] = make_int2(i, ei[i]);
  }
}

// ---------------- K2: per-node edge aggregation (atomic-free) ----------------
// One wave per dst node; lane = feature. Edge weights (rows 128..159) in VGPRs.
__global__ __launch_bounds__(256, 3) void edge_agg(
    const int* __restrict__ offsets, const int2* __restrict__ epair,
    const float* __restrict__ eattr, const float* __restrict__ Wf,
    const float* __restrict__ Ws, const float* __restrict__ Pdst,
    const float* __restrict__ Psrc, float* __restrict__ agg, int N,
    int nWaves) {
  const int lane = threadIdx.x & 63;
  const int wid = __builtin_amdgcn_readfirstlane(
      blockIdx.x * (blockDim.x >> 6) + (threadIdx.x >> 6));
  float wf[32], wsr[32];
#pragma unroll
  for (int k = 0; k < 32; ++k) {
    wf[k] = Wf[(128 + k) * 64 + lane];
    wsr[k] = Ws[(128 + k) * 64 + lane];
  }
  for (int n = wid; n < N; n += nWaves) {
    const int o0 = __builtin_amdgcn_readfirstlane(offsets[n]);
    const int o1 = __builtin_amdgcn_readfirstlane(offsets[n + 1]);
    const float fb = Pdst[(size_t)n * 128 + lane];
    const float sb = Pdst[(size_t)n * 128 + 64 + lane];
    float acc = 0.f;
    for (int j = o0; j < o1; ++j) {
      int2 p = epair[j];
      const int ex = __builtin_amdgcn_readfirstlane(p.x);
      const int sr = __builtin_amdgcn_readfirstlane(p.y);
      const float* er = eattr + (size_t)ex * 32;
      const float* pr = Psrc + (size_t)sr * 128;
      float f = fb + pr[lane];
      float s = sb + pr[64 + lane];
#pragma unroll
      for (int k = 0; k < 32; k += 4) {
        float4 ev = *(const float4*)(er + k);
        f = fmaf(ev.x, wf[k], f);     s = fmaf(ev.x, wsr[k], s);
        f = fmaf(ev.y, wf[k + 1], f); s = fmaf(ev.y, wsr[k + 1], s);
        f = fmaf(ev.z, wf[k + 2], f); s = fmaf(ev.z, wsr[k + 2], s);
        f = fmaf(ev.w, wf[k + 3], f); s = fmaf(ev.w, wsr[k + 3], s);
      }
      float sig = __builtin_amdgcn_rcpf(1.0f + __expf(-f));
      float sp = fmaxf(s, 0.f) + __logf(1.0f + __expf(-fabsf(s)));
      acc += sig * sp;
    }
    agg[(size_t)n * 64 + lane] = acc;
  }
}

// ---------------- K3: per-feature reductions over agg and x ----------------
__global__ __launch_bounds__(256) void stats_kernel(
    const float* __restrict__ agg, const float* __restrict__ x,
    float* __restrict__ stats, int N) {
  const int f = threadIdx.x & 63;
  const int sub = threadIdx.x >> 6;
  float sa = 0, sa2 = 0, sx = 0, sx2 = 0, sax = 0;
  for (int r = blockIdx.x * 4 + sub; r < N; r += gridDim.x * 4) {
    float a = agg[(size_t)r * 64 + f];
    float xv = x[(size_t)r * 64 + f];
    sa += a; sa2 += a * a; sx += xv; sx2 += xv * xv; sax += a * xv;
  }
  __shared__ float lds[4][5][64];
  lds[sub][0][f] = sa; lds[sub][1][f] = sa2; lds[sub][2][f] = sx;
  lds[sub][3][f] = sx2; lds[sub][4][f] = sax;
  __syncthreads();
  if (sub == 0) {
#pragma unroll
    for (int i = 0; i < 5; ++i) {
      float v = lds[0][i][f] + lds[1][i][f] + lds[2][i][f] + lds[3][i][f];
      atomicAdd(&stats[i * 64 + f], v);
    }
  }
}

// ---------------- K4: finalize BN affine + analytic LN stats ----------------
__global__ __launch_bounds__(64) void finalize_stats(
    const float* __restrict__ stats, const float* __restrict__ bn_w,
    const float* __restrict__ bn_b, float* __restrict__ ab, int N) {
  const int f = threadIdx.x;
  const float Nf = (float)N;
  const float invN = 1.0f / Nf;
  float Sa = stats[f], Sa2 = stats[64 + f], Sx = stats[128 + f],
        Sx2 = stats[192 + f], Sax = stats[256 + f];
  float mu = Sa * invN;
  float var = Sa2 * invN - mu * mu;
  float alpha = bn_w[f] / sqrtf(var + EPSF);
  float beta = bn_b[f] - mu * alpha;
  float Sh = alpha * Sa + Nf * beta + Sx;
  float Sh2 = alpha * alpha * Sa2 + Sx2 + Nf * beta * beta +
              2.f * alpha * Sax + 2.f * alpha * beta * Sa + 2.f * beta * Sx;
#pragma unroll
  for (int o = 32; o > 0; o >>= 1) {
    Sh += __shfl_down(Sh, o);
    Sh2 += __shfl_down(Sh2, o);
  }
  ab[f] = alpha;
  ab[64 + f] = beta;
  if (f == 0) {
    float cnt = Nf * 64.0f;
    float mean = Sh / cnt;
    float msq = Sh2 / cnt - mean * mean;
    ab[128] = mean;
    ab[129] = 1.0f / (sqrtf(fmaxf(msq, 0.f)) + EPSF);
  }
}

// ---------------- K5: BN+residual+LN+softplus, pooled into graphs ------------
__global__ __launch_bounds__(256) void node_finish(
    const float* __restrict__ agg, const float* __restrict__ x,
    const int* __restrict__ batch, const float* __restrict__ ab,
    const float* __restrict__ ln_w, const float* __restrict__ ln_b,
    float* __restrict__ add_pool, float* __restrict__ counts, int N,
    int chunk) {
  const int f = threadIdx.x & 63;
  const int sub = threadIdx.x >> 6;
  const int r0 = blockIdx.x * chunk;
  const int r1 = min(N, r0 + chunk);
  const float alpha = ab[f], beta = ab[64 + f];
  const float mean = ab[128], rden = ab[129];
  const float lw = ln_w[f] * rden;
  const float lb = ln_b[f];
  float acc = 0.f, cacc = 0.f;
  int curg = -1;
  for (int r = r0 + sub; r < r1; r += 4) {
    int g = batch[r];
    if (g != curg) {
      if (curg >= 0) {
        atomicAdd(&add_pool[(size_t)curg * 64 + f], acc);
        if (f == 0) atomicAdd(&counts[curg], cacc);
      }
      curg = g; acc = 0.f; cacc = 0.f;
    }
    float h = fmaf(alpha, agg[(size_t)r * 64 + f], beta) + x[(size_t)r * 64 + f];
    float v = (h - mean) * lw + lb;
    float sp = fmaxf(v, 0.f) + __logf(1.0f + __expf(-fabsf(v)));
    acc += sp; cacc += 1.f;
  }
  if (curg >= 0) {
    atomicAdd(&add_pool[(size_t)curg * 64 + f], acc);
    if (f == 0) atomicAdd(&counts[curg], cacc);
  }
}

// ---------------- K6: graph head ----------------
__global__ __launch_bounds__(1024) void graph_out(
    const float* __restrict__ add_pool, const float* __restrict__ counts,
    const float* __restrict__ Wl, const float* __restrict__ bl,
    const float* __restrict__ w4, const float* __restrict__ b4,
    float* __restrict__ out, int G) {
  const int t = threadIdx.x;
  const int g = t >> 1, c = t & 1;
  float cnt = fmaxf(counts[g], 1.0f);
  float inv = 1.0f / cnt;
  const float* ap = add_pool + (size_t)g * 64;
  float v = bl[c];
#pragma unroll 8
  for (int k = 0; k < 64; ++k)
    v = fmaf(ap[k], fmaf(Wl[k * 2 + c], inv, Wl[(64 + k) * 2 + c]), v);

  __shared__ float red[16];
  __shared__ float bc[2];
  float sum = v;
#pragma unroll
  for (int o = 32; o > 0; o >>= 1) sum += __shfl_down(sum, o);
  if ((t & 63) == 0) red[t >> 6] = sum;
  __syncthreads();
  if (t == 0) {
    float tot = 0;
#pragma unroll
    for (int i = 0; i < 16; ++i) tot += red[i];
    bc[0] = tot * (1.0f / 1024.0f);
  }
  __syncthreads();
  const float mean = bc[0];
  const float xc = v - mean;
  float sq = xc * xc;
  __syncthreads();
#pragma unroll
  for (int o = 32; o > 0; o >>= 1) sq += __shfl_down(sq, o);
  if ((t & 63) == 0) red[t >> 6] = sq;
  __syncthreads();
  if (t == 0) {
    float tot = 0;
#pragma unroll
    for (int i = 0; i < 16; ++i) tot += red[i];
    bc[1] = 1.0f / (sqrtf(tot * (1.0f / 1024.0f)) + EPSF);
  }
  __syncthreads();
  out[t] = xc * bc[1] * w4[c] + b4[c];
}

extern "C" void kernel_launch(void* const* d_in, const int* in_sizes, int n_in,
                              void* d_out, int out_size, void* d_ws,
                              size_t ws_size, hipStream_t stream) {
  const float* x = (const float*)d_in[0];
  const int* ei = (const int*)d_in[1];
  const float* eattr = (const float*)d_in[2];
  const int* batch = (const int*)d_in[3];
  const float* Wf = (const float*)d_in[4];
  const float* bf = (const float*)d_in[5];
  const float* Ws = (const float*)d_in[6];
  const float* bs = (const float*)d_in[7];
  const float* bn_w = (const float*)d_in[8];
  const float* bn_b = (const float*)d_in[9];
  const float* ln_w = (const float*)d_in[10];
  const float* ln_b = (const float*)d_in[11];
  const float* Wl = (const float*)d_in[12];
  const float* bl = (const float*)d_in[13];
  const float* w4 = (const float*)d_in[14];
  const float* b4 = (const float*)d_in[15];

  const int N = in_sizes[0] / 64;
  const int E = in_sizes[2] / 32;
  const int G = 512;

  float* ws = (float*)d_ws;
  float* agg = ws;                                   // N*64
  int* offsets = (int*)(agg + (size_t)N * 64);       // N+4
  float* stats = (float*)(offsets + N + 4);          // 320   [zeroed]
  float* add_pool = stats + 320;                     // G*64  [zeroed]
  float* counts = add_pool + (size_t)G * 64;         // G     [zeroed]
  int* deg = (int*)(counts + G);                     // N     [zeroed]
  int* cursor = deg + N;                             // N
  float* ab = (float*)(cursor + N);                  // 132
  int2* epair = (int2*)(ab + 132);                   // E int2
  float* Pdst = (float*)((int*)epair + 2 * (size_t)E);  // N*128
  float* Psrc = Pdst + (size_t)N * 128;              // N*128

  size_t zeroFloats = 320 + (size_t)G * 64 + G + N;
  hipMemsetAsync(stats, 0, zeroFloats * sizeof(float), stream);

  node_gemm<<<2048, 256, 0, stream>>>(x, Wf, bf, Ws, bs, Pdst, Psrc, N);
  hist_kernel<<<(E + 255) / 256, 256, 0, stream>>>(ei, deg, E);
  scan_kernel<<<1, 1024, 0, stream>>>(deg, offsets, cursor, N);
  scatter_kernel<<<(E + 255) / 256, 256, 0, stream>>>(ei, cursor, epair, E);
  edge_agg<<<2048, 256, 0, stream>>>(offsets, epair, eattr, Wf, Ws, Pdst, Psrc,
                                     agg, N, 2048 * 4);
  stats_kernel<<<512, 256, 0, stream>>>(agg, x, stats, N);
  finalize_stats<<<1, 64, 0, stream>>>(stats, bn_w, bn_b, ab, N);
  const int chunk = (N + 511) / 512;
  node_finish<<<512, 256, 0, stream>>>(agg, x, batch, ab, ln_w, ln_b, add_pool,
                                       counts, N, chunk);
  graph_out<<<1, 1024, 0, stream>>>(add_pool, counts, Wl, bl, w4, b4,
                                    (float*)d_out, G);
}